// Round 5
// baseline (102.870 us; speedup 1.0000x reference)
//
#include <hip/hip_runtime.h>
#include <math.h>

// Problem constants (match reference)
#define Bdim 8
#define Lq   256
#define Hd   128
#define NHd  4

static constexpr float kNEG = -4294967295.0f;           // -(2^32)+1 as f32
static constexpr float kScale = 0.17677669529663687f;   // 1/sqrt(32)

// async global->LDS DMA, 16B per lane. LDS dest = wave-uniform base + lane*16.
__device__ __forceinline__ void gld_lds16(const void* gptr, void* lptr) {
    __builtin_amdgcn_global_load_lds(
        (const __attribute__((address_space(1))) void*)gptr,
        (__attribute__((address_space(3))) void*)lptr, 16, 0, 0);
}

// ---------------------------------------------------------------------------
// prep: blocks 0-11 transpose Wq/Wk/Wv (64x64 LDS tiles, coalesced both ways);
//       block 12 normalizes the bool time_mask (u8 vs i32 auto-detect).
// ---------------------------------------------------------------------------
__global__ __launch_bounds__(256) void prep_kernel(
    const float* __restrict__ Wq, const float* __restrict__ Wk,
    const float* __restrict__ Wv, const unsigned char* __restrict__ raw,
    float* __restrict__ Wt, int* __restrict__ outmask)
{
    const int blk = blockIdx.x;
    if (blk < 12) {
        __shared__ float tile[64][65];
        const int mi = blk >> 2;
        const float* W = (mi == 0) ? Wq : (mi == 1) ? Wk : Wv;
        float* WT = Wt + mi * (Hd * Hd);
        const int ti = blk & 3;
        const int r0 = (ti >> 1) * 64, c0 = (ti & 1) * 64;
        #pragma unroll
        for (int k = 0; k < 16; ++k) {
            const int e = threadIdx.x + k * 256;
            const int r = e >> 6, c = e & 63;
            tile[r][c] = W[(r0 + r) * Hd + (c0 + c)];
        }
        __syncthreads();
        #pragma unroll
        for (int k = 0; k < 16; ++k) {
            const int e = threadIdx.x + k * 256;
            const int r = e >> 6, c = e & 63;
            WT[(c0 + r) * Hd + (r0 + c)] = tile[c][r];
        }
    } else {
        __shared__ int cnt;
        if (threadIdx.x == 0) cnt = 0;
        __syncthreads();
        const int n = Bdim * Lq;
        for (int i = threadIdx.x; i < n; i += 256)
            if ((i & 3) && raw[i]) atomicAdd(&cnt, 1);
        __syncthreads();
        const bool is_u8 = (cnt > 0);
        const int* raw32 = (const int*)raw;
        for (int i = threadIdx.x; i < n; i += 256) {
            const int v = is_u8 ? (int)raw[i] : raw32[i];
            outmask[i] = (v != 0) ? 1 : 0;
        }
    }
}

// ---------------------------------------------------------------------------
// Projections (fused abs_pos adds), W pre-transposed so loads are coalesced.
// 512 threads (8 waves/block): o = tid&127, rh = tid>>7, 2 rows/thread.
// ---------------------------------------------------------------------------
__global__ __launch_bounds__(512) void proj_kernel(
    const float* __restrict__ queries, const float* __restrict__ keys,
    const float* __restrict__ absK, const float* __restrict__ absV,
    const float* __restrict__ Wt,
    const float* __restrict__ bq, const float* __restrict__ bk,
    const float* __restrict__ bv,
    float* __restrict__ Qb, float* __restrict__ Kb, float* __restrict__ Vb)
{
    constexpr int R = 8;
    __shared__ float xq[R][Hd];
    __shared__ float xk[R][Hd];
    const int row0 = blockIdx.x * R;
    const int tid = threadIdx.x;
    #pragma unroll
    for (int k = 0; k < 2; ++k) {
        const int e = tid + k * 512;
        const int r = e >> 7, c = e & 127;
        xq[r][c] = queries[(row0 + r) * Hd + c];
        xk[r][c] = keys[(row0 + r) * Hd + c];
    }
    __syncthreads();

    const int o = tid & 127, rh = tid >> 7;
    const int r0 = rh * 2, r1 = rh * 2 + 1;
    const float* __restrict__ Wtq = Wt;
    const float* __restrict__ Wtk = Wt + Hd * Hd;
    const float* __restrict__ Wtv = Wt + 2 * Hd * Hd;

    float qa0 = bq[o], qa1 = qa0;
    float ka0 = bk[o] + absK[(row0 + r0) * Hd + o];
    float ka1 = bk[o] + absK[(row0 + r1) * Hd + o];
    float va0 = bv[o] + absV[(row0 + r0) * Hd + o];
    float va1 = bv[o] + absV[(row0 + r1) * Hd + o];

    #pragma unroll 4
    for (int i = 0; i < Hd; ++i) {
        const float wq = Wtq[i * Hd + o];
        const float wk = Wtk[i * Hd + o];
        const float wv = Wtv[i * Hd + o];
        const float x0 = xq[r0][i], x1 = xq[r1][i];
        const float y0 = xk[r0][i], y1 = xk[r1][i];
        qa0 += x0 * wq; qa1 += x1 * wq;
        ka0 += y0 * wk; ka1 += y1 * wk;
        va0 += y0 * wv; va1 += y1 * wv;
    }
    Qb[(row0 + r0) * Hd + o] = qa0;  Qb[(row0 + r1) * Hd + o] = qa1;
    Kb[(row0 + r0) * Hd + o] = ka0;  Kb[(row0 + r1) * Hd + o] = ka1;
    Vb[(row0 + r0) * Hd + o] = va0;  Vb[(row0 + r1) * Hd + o] = va1;
}

// ---------------------------------------------------------------------------
// Fused attention, one block per (b,l), 256 threads = 4 waves; wave w owns
// head w. Per 16-row tile: stage K+tK (or V+tV) into LDS via global_load_lds
// (4 KB in flight per wave -> HBM-BW-bound by TLP), sync, compute from LDS.
// XOR swizzle (unit ^ (row&7), 16B units) applied on BOTH the per-lane global
// source and the LDS read -> conflict-free ds_read_b128 (rule: both-sides-
// or-neither with global_load_lds's linear LDS write).
// Masked rows: uniform 1/256 fast path (exact). l bit-reversed across grid.
// ---------------------------------------------------------------------------
__global__ __launch_bounds__(256) void attn_kernel(
    const float* __restrict__ Qb, const float* __restrict__ Kb,
    const float* __restrict__ Vb,
    const float* __restrict__ tK, const float* __restrict__ tV,
    const int* __restrict__ tmask, float* __restrict__ out)
{
    const int bid = blockIdx.x;
    int rl = bid & 255;                         // bit-reverse 8 bits
    rl = ((rl & 0x55) << 1) | ((rl >> 1) & 0x55);
    rl = ((rl & 0x33) << 2) | ((rl >> 2) & 0x33);
    rl = ((rl & 0x0F) << 4) | ((rl >> 4) & 0x0F);
    const int l = rl;
    const int b = bid >> 8;
    const int tid = threadIdx.x;
    const int w = tid >> 6;                     // wave = head
    const int lane = tid & 63;
    const int c8 = (w << 2) | (tid & 3);        // 8-float channel group
    const int m_off = (tid >> 2) & 15;

    __shared__ float sc[NHd][Lq];               // 4 KB scores
    __shared__ float bufA[2048];                // 8 KB: K / V tile (16x128)
    __shared__ float bufB[2048];                // 8 KB: tK / tV tile

    const size_t rowbase = ((size_t)b * Lq + l) * Hd;
    const float4 q0 = *(const float4*)(Qb + rowbase + c8 * 8);
    const float4 q1 = *(const float4*)(Qb + rowbase + c8 * 8 + 4);

    const char* Kslab = (const char*)(Kb + (size_t)b * Lq * Hd);
    const char* Vslab = (const char*)(Vb + (size_t)b * Lq * Hd);
    const char* tKrow = (const char*)(tK + rowbase * Lq);
    const char* tVrow = (const char*)(tV + rowbase * Lq);

    // staging: tile = 512 16B-units; this thread's linear slots + swizzled src
    const int s0 = w * 128 + lane, s1 = s0 + 64;
    const int g0 = (s0 ^ ((s0 >> 5) & 7)) * 16;
    const int g1 = (s1 ^ ((s1 >> 5) & 7)) * 16;
    char* ldsA0 = (char*)bufA + (w * 128) * 16;      // wave-uniform dests
    char* ldsA1 = (char*)bufA + (w * 128 + 64) * 16;
    char* ldsB0 = (char*)bufB + (w * 128) * 16;
    char* ldsB1 = (char*)bufB + (w * 128 + 64) * 16;

    // swizzled read slots (constant): unit (m_off, c8*2+j) ^ (m_off&7)
    const int su0 = ((m_off * 32 + c8 * 2)     ^ (m_off & 7)) * 16;
    const int su1 = ((m_off * 32 + c8 * 2 + 1) ^ (m_off & 7)) * 16;
    const float4* rdA0 = (const float4*)((char*)bufA + su0);
    const float4* rdA1 = (const float4*)((char*)bufA + su1);
    const float4* rdB0 = (const float4*)((char*)bufB + su0);
    const float4* rdB1 = (const float4*)((char*)bufB + su1);

    const bool rowmask = (tmask[b * Lq + l] != 0);
    const int nt = (l >> 4) + 1;                // tiles of 16 m-rows

    if (!rowmask) {
        // ---- phase 1: scores sc[w][m] = (Q.(Keff[m]+tK[l,m]))*scale ----
        for (int t = 0; t < nt; ++t) {
            const size_t tb = (size_t)t * 8192;
            gld_lds16(Kslab + tb + g0, ldsA0);
            gld_lds16(Kslab + tb + g1, ldsA1);
            gld_lds16(tKrow + tb + g0, ldsB0);
            gld_lds16(tKrow + tb + g1, ldsB1);
            __syncthreads();                    // drains DMA, tile ready
            const float4 k0 = *rdA0, k1 = *rdA1;
            const float4 t0 = *rdB0, t1 = *rdB1;
            float p = q0.x * (k0.x + t0.x) + q0.y * (k0.y + t0.y)
                    + q0.z * (k0.z + t0.z) + q0.w * (k0.w + t0.w)
                    + q1.x * (k1.x + t1.x) + q1.y * (k1.y + t1.y)
                    + q1.z * (k1.z + t1.z) + q1.w * (k1.w + t1.w);
            p += __shfl_xor(p, 1);
            p += __shfl_xor(p, 2);
            const int m = t * 16 + m_off;
            if ((tid & 3) == 0) sc[w][m] = (m <= l) ? p * kScale : kNEG;
            __syncthreads();                    // protect buffers for next t
        }

        // ---- softmax, wave-local on own head; every tile read guarded ----
        {
            float v0s = (lane       <= l) ? sc[w][lane]       : kNEG;
            float v1s = (lane + 64  <= l) ? sc[w][lane + 64]  : kNEG;
            float v2s = (lane + 128 <= l) ? sc[w][lane + 128] : kNEG;
            float v3s = (lane + 192 <= l) ? sc[w][lane + 192] : kNEG;
            float mx = fmaxf(fmaxf(v0s, v1s), fmaxf(v2s, v3s));
            #pragma unroll
            for (int d = 1; d < 64; d <<= 1) mx = fmaxf(mx, __shfl_xor(mx, d));
            v0s = expf(v0s - mx); v1s = expf(v1s - mx);
            v2s = expf(v2s - mx); v3s = expf(v3s - mx);
            float ssum = v0s + v1s + v2s + v3s;
            #pragma unroll
            for (int d = 1; d < 64; d <<= 1) ssum += __shfl_xor(ssum, d);
            const float inv = 1.0f / ssum;
            // writeback covers ALL 256 entries; m>l become exact 0
            sc[w][lane]       = v0s * inv;
            sc[w][lane + 64]  = v1s * inv;
            sc[w][lane + 128] = v2s * inv;
            sc[w][lane + 192] = v3s * inv;
        }
        // no barrier needed: sc[w] is produced and consumed by wave w only
    }

    // ---- phase 2: out[c] = sum_m A[m] * (Veff[m,c] + tV[l,m,c]) ----
    const int nto = rowmask ? (Lq / 16) : nt;
    float4 acc0 = {0.f, 0.f, 0.f, 0.f}, acc1 = {0.f, 0.f, 0.f, 0.f};
    for (int t = 0; t < nto; ++t) {
        const size_t tb = (size_t)t * 8192;
        gld_lds16(Vslab + tb + g0, ldsA0);
        gld_lds16(Vslab + tb + g1, ldsA1);
        gld_lds16(tVrow + tb + g0, ldsB0);
        gld_lds16(tVrow + tb + g1, ldsB1);
        __syncthreads();
        const float aw = rowmask ? 0.00390625f : sc[w][t * 16 + m_off];
        const float4 v0 = *rdA0, v1 = *rdA1;
        const float4 t0 = *rdB0, t1 = *rdB1;
        acc0.x += aw * (v0.x + t0.x); acc0.y += aw * (v0.y + t0.y);
        acc0.z += aw * (v0.z + t0.z); acc0.w += aw * (v0.w + t0.w);
        acc1.x += aw * (v1.x + t1.x); acc1.y += aw * (v1.y + t1.y);
        acc1.z += aw * (v1.z + t1.z); acc1.w += aw * (v1.w + t1.w);
        __syncthreads();
    }
    // reduce across the 16 m_off lane-groups (bits 2..5 of lane)
    #pragma unroll
    for (int d = 4; d < 64; d <<= 1) {
        acc0.x += __shfl_xor(acc0.x, d); acc0.y += __shfl_xor(acc0.y, d);
        acc0.z += __shfl_xor(acc0.z, d); acc0.w += __shfl_xor(acc0.w, d);
        acc1.x += __shfl_xor(acc1.x, d); acc1.y += __shfl_xor(acc1.y, d);
        acc1.z += __shfl_xor(acc1.z, d); acc1.w += __shfl_xor(acc1.w, d);
    }
    if (m_off == 0) {
        *(float4*)(out + rowbase + c8 * 8)     = acc0;
        *(float4*)(out + rowbase + c8 * 8 + 4) = acc1;
    }
}

// ---------------------------------------------------------------------------
extern "C" void kernel_launch(void* const* d_in, const int* in_sizes, int n_in,
                              void* d_out, int out_size, void* d_ws, size_t ws_size,
                              hipStream_t stream) {
    const float* queries = (const float*)d_in[0];
    const float* keys    = (const float*)d_in[1];
    const float* tK      = (const float*)d_in[2];
    const float* tV      = (const float*)d_in[3];
    const float* absK    = (const float*)d_in[4];
    const float* absV    = (const float*)d_in[5];
    const float* Wq      = (const float*)d_in[6];
    const float* bq      = (const float*)d_in[7];
    const float* Wk      = (const float*)d_in[8];
    const float* bk      = (const float*)d_in[9];
    const float* Wv      = (const float*)d_in[10];
    const float* bv      = (const float*)d_in[11];
    const unsigned char* tmask_raw = (const unsigned char*)d_in[12];
    // d_in[13] (attn_mask) is deterministic triu(k=1) -> handled in-kernel.

    float* outp = (float*)d_out;

    const int rows = Bdim * Lq;                    // 2048
    float* Qb = (float*)d_ws;                      // 1 MB
    float* Kb = Qb + (size_t)rows * Hd;            // 1 MB
    float* Vb = Kb + (size_t)rows * Hd;            // 1 MB
    int* tmask = (int*)(Vb + (size_t)rows * Hd);   // 8 KB
    float* Wt = (float*)(tmask + rows);            // 192 KB (3 transposed W)

    prep_kernel<<<13, 256, 0, stream>>>(Wq, Wk, Wv, tmask_raw, Wt, tmask);
    proj_kernel<<<rows / 8, 512, 0, stream>>>(queries, keys, absK, absV, Wt,
                                              bq, bk, bv, Qb, Kb, Vb);
    attn_kernel<<<rows, 256, 0, stream>>>(Qb, Kb, Vb, tK, tV, tmask, outp);
}